// Round 7
// baseline (1175.636 us; speedup 1.0000x reference)
//
#include <hip/hip_runtime.h>
#include <cstdint>
#include <cstddef>

typedef __attribute__((ext_vector_type(8))) short short8;       // 8 x bf16 bits (MFMA A/B frag)
typedef __attribute__((ext_vector_type(4))) float floatx4;      // MFMA C/D frag
typedef __attribute__((ext_vector_type(4))) unsigned int uintx4;

#define DEV static __device__ __forceinline__

constexpr int NT = 2, NB = 16, NC = 256, NN = 4096, NHD = 8;
constexpr size_t NE1 = (size_t)NT * NB * NC * NN;   // elements per output tensor
constexpr size_t TSTRIDE = (size_t)NB * NC * NN;    // t-stride in elements

// ---------- helpers ----------
DEV unsigned short f2bf(float x) {            // round-to-nearest-even fp32 -> bf16 bits
  unsigned int u = __builtin_bit_cast(unsigned int, x);
  unsigned int lsb = (u >> 16) & 1u;
  u += 0x7FFFu + lsb;
  return (unsigned short)(u >> 16);
}
DEV float bfb2f(unsigned short h) {
  unsigned int u = ((unsigned int)h) << 16;
  return __builtin_bit_cast(float, u);
}
DEV unsigned int pk2(unsigned short a, unsigned short b) {
  return (unsigned int)a | ((unsigned int)b << 16);
}
// unpack 8 bits (at bit positions quad*8+j of a bpermuted u32) to a bf16 frag
DEV short8 bits2frag(unsigned int w, int quad) {
  short8 f;
  #pragma unroll
  for (int j = 0; j < 8; j++)
    f[j] = (short)(((w >> (quad * 8 + j)) & 1) ? 0x3F80 : 0);
  return f;
}

// ---------- kernel 1: weight split + BN constant prep ----------
__global__ __launch_bounds__(256) void prep_kernel(
    const float* __restrict__ wq, const float* __restrict__ wk, const float* __restrict__ wv,
    const float* __restrict__ wp, const float* __restrict__ bp,
    const float* __restrict__ qg, const float* __restrict__ qb, const float* __restrict__ qm, const float* __restrict__ qva,
    const float* __restrict__ kg, const float* __restrict__ kb, const float* __restrict__ km, const float* __restrict__ kva,
    const float* __restrict__ vg, const float* __restrict__ vb, const float* __restrict__ vm, const float* __restrict__ vva,
    const float* __restrict__ pg, const float* __restrict__ pb, const float* __restrict__ pm, const float* __restrict__ pva,
    unsigned short* __restrict__ Wqkv, unsigned short* __restrict__ Wp,
    float* __restrict__ invqkv, float* __restrict__ shqkv,
    float* __restrict__ invp, float* __restrict__ shp)
{
  int idx = blockIdx.x * 256 + threadIdx.x;
  if (idx < 196608) {                       // Wq|Wk|Wv stacked [768][256], 3-way bf16 split
    int o = idx >> 8, c = idx & 255;
    const float* src = (o < 256) ? wq : (o < 512) ? wk : wv;
    float w = src[(size_t)(o & 255) * 256 + c];
    unsigned short h0 = f2bf(w);  float f0 = bfb2f(h0);
    float r1 = w - f0;
    unsigned short h1 = f2bf(r1); float f1 = bfb2f(h1);
    float r2 = r1 - f1;
    unsigned short h2 = f2bf(r2);
    Wqkv[idx] = h0; Wqkv[196608 + idx] = h1; Wqkv[393216 + idx] = h2;
  } else if (idx < 262144) {                // Wp [256][256], 3-way split
    int j = idx - 196608;
    float w = wp[j];
    unsigned short h0 = f2bf(w);  float f0 = bfb2f(h0);
    float r1 = w - f0;
    unsigned short h1 = f2bf(r1); float f1 = bfb2f(h1);
    float r2 = r1 - f1;
    unsigned short h2 = f2bf(r2);
    Wp[j] = h0; Wp[65536 + j] = h1; Wp[131072 + j] = h2;
  } else if (idx < 262912) {                // BN constants for q,k,v stacked [768]
    int i = idx - 262144;
    int p = i >> 8, c = i & 255;
    float g  = (p == 0) ? qg[c] : (p == 1) ? kg[c] : vg[c];
    float be = (p == 0) ? qb[c] : (p == 1) ? kb[c] : vb[c];
    float mn = (p == 0) ? qm[c] : (p == 1) ? km[c] : vm[c];
    float vr = (p == 0) ? qva[c] : (p == 1) ? kva[c] : vva[c];
    float sq = sqrtf(vr + 1e-5f);
    invqkv[i] = g / sq;
    shqkv[i]  = be - (mn * g) / sq;
  } else if (idx < 263168) {                // BN constants for p, bias folded in
    int c = idx - 262912;
    float sq = sqrtf(pva[c] + 1e-5f);
    float iv = pg[c] / sq;
    invp[c] = iv;
    shp[c]  = pb[c] - (pm[c] * pg[c]) / sq + bp[c] * iv;
  }
}

// ---------- kernel 2: LIF on x -> xs (fp32 [t,b,c,n]) + bit-plane xbits [z][n][c-word] ----------
__global__ __launch_bounds__(256) void lifx_kernel(const float* __restrict__ x,
                                                   float* __restrict__ xs_out,
                                                   unsigned short* __restrict__ xb16)
{
  __shared__ float tile[2][64][65];
  const int nt = blockIdx.x, ct = blockIdx.y, b = blockIdx.z;
  const int tid = threadIdx.x;
  const int ci = tid >> 2, cq = tid & 3;
  const int n0 = nt * 64, c0 = ct * 64;
  const size_t rowbase = ((size_t)(b * NC + c0 + ci)) * NN + n0 + cq * 16;
  const float* px0 = x + rowbase;
  const float* px1 = x + rowbase + TSTRIDE;
  float* po0 = xs_out + rowbase;
  float* po1 = xs_out + rowbase + TSTRIDE;
  #pragma unroll
  for (int jj = 0; jj < 4; jj++) {
    floatx4 x0 = *(const floatx4*)(px0 + jj * 4);
    floatx4 x1 = *(const floatx4*)(px1 + jj * 4);
    floatx4 s0v, s1v;
    #pragma unroll
    for (int e = 0; e < 4; e++) {
      float v1 = x0[e] * 0.5f;                       // exact
      float s0 = (v1 >= 1.0f) ? 1.0f : 0.0f;
      float vr = v1 * (1.0f - s0);                   // exact (0 or v1)
      float v2 = vr + (x1[e] - vr) * 0.5f;           // same rounding as reference
      float s1 = (v2 >= 1.0f) ? 1.0f : 0.0f;
      s0v[e] = s0; s1v[e] = s1;
      tile[0][ci][cq * 16 + jj * 4 + e] = s0;
      tile[1][ci][cq * 16 + jj * 4 + e] = s1;
    }
    *(floatx4*)(po0 + jj * 4) = s0v;
    *(floatx4*)(po1 + jj * 4) = s1v;
  }
  __syncthreads();
  const int ni = tid >> 2, cg = tid & 3;   // thread owns row n0+ni, c-word (c0>>4)+cg
  #pragma unroll
  for (int t = 0; t < 2; t++) {
    unsigned int wbits = 0;
    #pragma unroll
    for (int j = 0; j < 16; j++)
      wbits |= (tile[t][cg * 16 + j][ni] != 0.f ? 1u : 0u) << j;
    xb16[((size_t)((t * NB + b) * NN) + n0 + ni) * 16 + (c0 >> 4) + cg] = (unsigned short)wbits;
  }
}

// ---------- kernel 3: fused QKV GEMM + BN + LIF — barrier-free K-loop ----------
// A-frags loaded directly from L2-resident weights (no LDS staging); B-frags built from
// lane-held bit-words via ds_bpermute.  Per-acc MFMA sequence identical to prior rounds
// (chunk-ascending, s0/s1/s2 per mi) => bit-identical results.
__global__ __launch_bounds__(256, 3) void qkv_gemm(
    const unsigned int* __restrict__ xb32,    // [z][n][8 u32 c-words]
    const unsigned short* __restrict__ Wsp,   // [3 splits][768][256] bf16
    const float* __restrict__ invv, const float* __restrict__ shv,  // [768]
    float* __restrict__ dq, float* __restrict__ dk, float* __restrict__ dv,
    unsigned short* __restrict__ qbits, unsigned short* __restrict__ kbits,
    unsigned short* __restrict__ vbits)
{
  __shared__ float yl[128 * 65];              // t0<->t1 exchange (epilogue only)
  const int nt = blockIdx.x, mt = blockIdx.y, b = blockIdx.z;
  const int tid = threadIdx.x;
  const int lane = tid & 63, quad = lane >> 4, l16 = lane & 15;
  const int wave = tid >> 6;
  const int tw = wave >> 1, wm = (wave & 1) * 64;   // waves 0,1: t=0 ; waves 2,3: t=1
  floatx4 acc[4][4] = {};
  // lane-owned B bit-words: row n = nt*64 + lane, t = tw (8 u32 = whole K)
  const unsigned int* xr = xb32 + ((size_t)((tw * NB + b) * NN) + nt * 64 + lane) * 8;
  uintx4 xw0 = *(const uintx4*)xr;
  uintx4 xw1 = *(const uintx4*)(xr + 4);
  // A element-offsets per (s, mi) — uniform base Wsp+k0 added per chunk (saddr form)
  int voff[12];
  #pragma unroll
  for (int s = 0; s < 3; s++)
    #pragma unroll
    for (int mi = 0; mi < 4; mi++)
      voff[s * 4 + mi] = s * 196608 + (mt * 128 + wm + mi * 16 + l16) * 256 + quad * 8;

  #pragma unroll
  for (int kc = 0; kc < 8; kc++) {            // K chunks of 32
    unsigned int myw = (kc < 4) ? ((const unsigned int*)&xw0)[kc] : ((const unsigned int*)&xw1)[kc - 4];
    short8 bfr[4];
    #pragma unroll
    for (int ni = 0; ni < 4; ni++) {
      unsigned int src = (unsigned int)__builtin_amdgcn_ds_bpermute((ni * 16 + l16) * 4, (int)myw);
      bfr[ni] = bits2frag(src, quad);
    }
    const unsigned short* gk = Wsp + kc * 32;        // uniform
    #pragma unroll
    for (int mi = 0; mi < 4; mi++) {
      short8 a0 = *(const short8*)(gk + voff[mi]);
      short8 a1 = *(const short8*)(gk + voff[4 + mi]);
      short8 a2 = *(const short8*)(gk + voff[8 + mi]);
      #pragma unroll
      for (int ni = 0; ni < 4; ni++) {
        acc[mi][ni] = __builtin_amdgcn_mfma_f32_16x16x32_bf16(a0, bfr[ni], acc[mi][ni], 0, 0, 0);
        acc[mi][ni] = __builtin_amdgcn_mfma_f32_16x16x32_bf16(a1, bfr[ni], acc[mi][ni], 0, 0, 0);
        acc[mi][ni] = __builtin_amdgcn_mfma_f32_16x16x32_bf16(a2, bfr[ni], acc[mi][ni], 0, 0, 0);
      }
    }
  }
  __syncthreads();
  if (tw == 0) {                   // t0 waves publish raw accumulators
    #pragma unroll
    for (int mi = 0; mi < 4; mi++)
      #pragma unroll
      for (int r = 0; r < 4; r++)
        #pragma unroll
        for (int ni = 0; ni < 4; ni++)
          yl[(size_t)(wm + mi * 16 + quad * 4 + r) * 65 + ni * 16 + l16] = acc[mi][ni][r];
  }
  __syncthreads();
  if (tw == 1) {                   // t1 waves apply BN + 2-step LIF, write both planes + bits
    #pragma unroll
    for (int mi = 0; mi < 4; mi++) {
      #pragma unroll
      for (int r = 0; r < 4; r++) {
        const int lrow = wm + mi * 16 + quad * 4 + r;
        const int orow = mt * 128 + lrow;
        const float iv = invv[orow], sh = shv[orow];
        const int widx = orow >> 8, c = orow & 255;
        float* dst = (widx == 0) ? dq : (widx == 1) ? dk : dv;
        unsigned short* bb = (widx == 0) ? qbits : (widx == 1) ? kbits : vbits;
        #pragma unroll
        for (int ni = 0; ni < 4; ni++) {
          const int n = nt * 64 + ni * 16 + l16;
          float y0 = yl[(size_t)lrow * 65 + ni * 16 + l16] * iv + sh;
          float y1 = acc[mi][ni][r] * iv + sh;
          float v1 = y0 * 0.5f;
          float s0 = (v1 >= 1.0f) ? 1.0f : 0.0f;
          float vr = v1 * (1.0f - s0);
          float v2 = vr + (y1 - vr) * 0.5f;
          float s1 = (v2 >= 1.0f) ? 1.0f : 0.0f;
          dst[(size_t)(b * NC + c) * NN + n] = s0;
          dst[(size_t)((NB + b) * NC + c) * NN + n] = s1;
          unsigned long long bl0 = __ballot(s0 != 0.0f);   // bit(lane)=quad*16+l16
          unsigned long long bl1 = __ballot(s1 != 0.0f);
          if (l16 == 0) {          // field quad = 16 n-bits of this lane's row c
            const int w16 = nt * 4 + ni;
            bb[(size_t)b        * 65536 + (size_t)c * 256 + w16] = (unsigned short)(bl0 >> (quad * 16));
            bb[(size_t)(NB + b) * 65536 + (size_t)c * 256 + w16] = (unsigned short)(bl1 >> (quad * 16));
          }
        }
      }
    }
  }
}

// ---------- kernel 4: kv = K^T V via popcount (exact ints) -> transposed hi/lo bf16 planes ----------
// hi = rne_bf16(v) (multiple of 16, exact), lo = v-hi (|lo|<=8, exact) — same split values
// attn used before, now computed once per (z,h) instead of per n-block.
__global__ __launch_bounds__(256) void kv_kernel(const unsigned long long* __restrict__ kb,
                                                 const unsigned long long* __restrict__ vb,
                                                 unsigned short* __restrict__ kvhiT,
                                                 unsigned short* __restrict__ kvloT)
{
  __shared__ unsigned long long Kl[32 * 65];
  __shared__ unsigned long long Vl[32 * 65];
  const int h = blockIdx.x, z = blockIdx.y;    // z = t*16+b
  const int tid = threadIdx.x;
  for (int i = tid; i < 2048; i += 256) {
    int row = i >> 6, w = i & 63;
    size_t g = (size_t)z * 16384 + (size_t)(h * 32 + row) * 64 + w;
    Kl[row * 65 + w] = kb[g];
    Vl[row * 65 + w] = vb[g];
  }
  __syncthreads();
  const int d = tid & 31, e0 = tid >> 5;       // thread: row d x 4 cols (e0+8p)
  int acc0 = 0, acc1 = 0, acc2 = 0, acc3 = 0;
  for (int w = 0; w < 64; w++) {
    unsigned long long ku = Kl[d * 65 + w];
    acc0 += __popcll(ku & Vl[(e0     ) * 65 + w]);
    acc1 += __popcll(ku & Vl[(e0 +  8) * 65 + w]);
    acc2 += __popcll(ku & Vl[(e0 + 16) * 65 + w]);
    acc3 += __popcll(ku & Vl[(e0 + 24) * 65 + w]);
  }
  unsigned short* oh = kvhiT + ((size_t)(z * NHD + h) << 10);  // layout [e][d]
  unsigned short* ol = kvloT + ((size_t)(z * NHD + h) << 10);
  int accs[4] = {acc0, acc1, acc2, acc3};
  #pragma unroll
  for (int p = 0; p < 4; p++) {
    float v = (float)accs[p];
    unsigned short hi = f2bf(v);
    float lo = v - bfb2f(hi);
    oh[(e0 + 8 * p) * 32 + d] = hi;
    ol[(e0 + 8 * p) * 32 + d] = f2bf(lo);
  }
}

// ---------- kernel 5: attn = 0.125*(q@kv) via exact-integer MFMA, LIF(0.5) -> s bit-plane ----------
__global__ __launch_bounds__(256) void attn_kernel(const unsigned short* __restrict__ qb16,
                                                   const unsigned short* __restrict__ kvhiT,
                                                   const unsigned short* __restrict__ kvloT,
                                                   unsigned short* __restrict__ sb16)
{
  __shared__ unsigned short qt[2][32][16];    // q bit-words: [t][d][n-word]
  const int nb = blockIdx.x, h = blockIdx.y, b = blockIdx.z;
  const int tid = threadIdx.x;
  const int wave = tid >> 6, lane = tid & 63, quad = lane >> 4, l16 = lane & 15;
  for (int i = tid; i < 1024; i += 256) {
    int t = i >> 9, j = i & 511, row = j >> 4, w = j & 15;
    qt[t][row][w] = qb16[(size_t)(t * NB + b) * 65536 + (size_t)(h * 32 + row) * 256 + nb * 16 + w];
  }
  // B-frags direct from transposed hi/lo planes (L2-hot): frag = [e=eh*16+l16][d=quad*8..+7]
  short8 bf[2][2][2];
  #pragma unroll
  for (int t = 0; t < 2; t++) {
    const unsigned short* kh = kvhiT + ((size_t)((t * NB + b) * NHD + h) << 10);
    const unsigned short* kl = kvloT + ((size_t)((t * NB + b) * NHD + h) << 10);
    #pragma unroll
    for (int eh = 0; eh < 2; eh++) {
      bf[t][0][eh] = *(const short8*)(kh + (eh * 16 + l16) * 32 + quad * 8);
      bf[t][1][eh] = *(const short8*)(kl + (eh * 16 + l16) * 32 + quad * 8);
    }
  }
  __syncthreads();
  floatx4 acc[2][4][2] = {};                   // [t][ntile][ehalf]
  #pragma unroll
  for (int t = 0; t < 2; t++) {
    #pragma unroll
    for (int nt = 0; nt < 4; nt++) {
      const int wv = wave * 4 + nt;            // n-word index of this tile
      short8 af;
      #pragma unroll
      for (int j = 0; j < 8; j++) {            // broadcast u16 read + per-lane bit test
        unsigned short w = qt[t][quad * 8 + j][wv];
        af[j] = (short)(((w >> l16) & 1) ? 0x3F80 : 0);
      }
      #pragma unroll
      for (int eh = 0; eh < 2; eh++) {
        acc[t][nt][eh] = __builtin_amdgcn_mfma_f32_16x16x32_bf16(af, bf[t][0][eh], acc[t][nt][eh], 0, 0, 0);
        acc[t][nt][eh] = __builtin_amdgcn_mfma_f32_16x16x32_bf16(af, bf[t][1][eh], acc[t][nt][eh], 0, 0, 0);
      }
    }
  }
  // epilogue: exact dyadic LIF(0.5); pack spikes as bits (16 c per n-row)
  const int n0 = nb * 256 + wave * 64;
  #pragma unroll
  for (int nt = 0; nt < 4; nt++) {
    #pragma unroll
    for (int r = 0; r < 4; r++) {
      const int n = n0 + nt * 16 + quad * 4 + r;          // per-lane (quad)
      #pragma unroll
      for (int eh = 0; eh < 2; eh++) {
        float a0 = acc[0][nt][eh][r] * 0.125f;            // exact dyadic
        float a1 = acc[1][nt][eh][r] * 0.125f;
        float v1 = a0 * 0.5f;
        float s0 = (v1 >= 0.5f) ? 1.f : 0.f;
        float vr = v1 * (1.f - s0);
        float v2 = vr + (a1 - vr) * 0.5f;
        float s1 = (v2 >= 0.5f) ? 1.f : 0.f;
        unsigned long long bl0 = __ballot(s0 != 0.f);     // field quad = 16 c-bits of n(quad)
        unsigned long long bl1 = __ballot(s1 != 0.f);
        if (l16 == 0) {
          const int w16 = h * 2 + eh;
          sb16[(size_t)b        * 65536 + (size_t)n * 16 + w16] = (unsigned short)(bl0 >> (quad * 16));
          sb16[(size_t)(NB + b) * 65536 + (size_t)n * 16 + w16] = (unsigned short)(bl1 >> (quad * 16));
        }
      }
    }
  }
}

// ---------- kernel 6: out = BN(Wp @ s + bp) — barrier-free K-loop, no LDS ----------
__global__ __launch_bounds__(256, 3) void p_gemm(
    const unsigned int* __restrict__ sb32,    // [z][n][8 u32 c-words]
    const unsigned short* __restrict__ Wsp,   // [3][256][256]
    const float* __restrict__ invv, const float* __restrict__ shv,
    float* __restrict__ dout)
{
  const int nt = blockIdx.x, mt = blockIdx.y, z = blockIdx.z;  // z = t*16+b
  const int tid = threadIdx.x;
  const int lane = tid & 63, quad = lane >> 4, l16 = lane & 15;
  const int wave = tid >> 6;
  const int wm = (wave & 1) * 64, wn = (wave >> 1) * 64;
  floatx4 acc[4][4] = {};
  // lane-owned B bit-words: row n = nt*128 + wn + lane
  const unsigned int* sr = sb32 + ((size_t)(z * NN) + nt * 128 + wn + lane) * 8;
  uintx4 sw0 = *(const uintx4*)sr;
  uintx4 sw1 = *(const uintx4*)(sr + 4);
  int voff[12];
  #pragma unroll
  for (int s = 0; s < 3; s++)
    #pragma unroll
    for (int mi = 0; mi < 4; mi++)
      voff[s * 4 + mi] = s * 65536 + (mt * 128 + wm + mi * 16 + l16) * 256 + quad * 8;

  #pragma unroll
  for (int kc = 0; kc < 8; kc++) {
    unsigned int myw = (kc < 4) ? ((const unsigned int*)&sw0)[kc] : ((const unsigned int*)&sw1)[kc - 4];
    short8 bfr[4];
    #pragma unroll
    for (int ni = 0; ni < 4; ni++) {
      unsigned int src = (unsigned int)__builtin_amdgcn_ds_bpermute((ni * 16 + l16) * 4, (int)myw);
      bfr[ni] = bits2frag(src, quad);
    }
    const unsigned short* gk = Wsp + kc * 32;
    #pragma unroll
    for (int mi = 0; mi < 4; mi++) {
      short8 a0 = *(const short8*)(gk + voff[mi]);
      short8 a1 = *(const short8*)(gk + voff[4 + mi]);
      short8 a2 = *(const short8*)(gk + voff[8 + mi]);
      #pragma unroll
      for (int ni = 0; ni < 4; ni++) {
        acc[mi][ni] = __builtin_amdgcn_mfma_f32_16x16x32_bf16(a0, bfr[ni], acc[mi][ni], 0, 0, 0);
        acc[mi][ni] = __builtin_amdgcn_mfma_f32_16x16x32_bf16(a1, bfr[ni], acc[mi][ni], 0, 0, 0);
        acc[mi][ni] = __builtin_amdgcn_mfma_f32_16x16x32_bf16(a2, bfr[ni], acc[mi][ni], 0, 0, 0);
      }
    }
  }
  #pragma unroll
  for (int mi = 0; mi < 4; mi++) {
    #pragma unroll
    for (int r = 0; r < 4; r++) {
      const int orow = mt * 128 + wm + mi * 16 + quad * 4 + r;
      const float iv = invv[orow], sh = shv[orow];
      #pragma unroll
      for (int ni = 0; ni < 4; ni++) {
        const int n = nt * 128 + wn + ni * 16 + l16;
        dout[((size_t)(z * NC + orow)) * NN + n] = acc[mi][ni][r] * iv + sh;
      }
    }
  }
}

// ---------- launch ----------
extern "C" void kernel_launch(void* const* d_in, const int* in_sizes, int n_in,
                              void* d_out, int out_size, void* d_ws, size_t ws_size,
                              hipStream_t stream) {
  (void)in_sizes; (void)n_in; (void)out_size; (void)ws_size;
  const float* x  = (const float*)d_in[0];
  const float* wq = (const float*)d_in[1];
  const float* wk = (const float*)d_in[2];
  const float* wv = (const float*)d_in[3];
  const float* wp = (const float*)d_in[4];
  const float* bp = (const float*)d_in[5];
  const float* qg = (const float*)d_in[6],  *qb = (const float*)d_in[7];
  const float* qm = (const float*)d_in[8],  *qva = (const float*)d_in[9];
  const float* kg = (const float*)d_in[10], *kb = (const float*)d_in[11];
  const float* km = (const float*)d_in[12], *kva = (const float*)d_in[13];
  const float* vg = (const float*)d_in[14], *vb = (const float*)d_in[15];
  const float* vm = (const float*)d_in[16], *vva = (const float*)d_in[17];
  const float* pg = (const float*)d_in[18], *pb = (const float*)d_in[19];
  const float* pm = (const float*)d_in[20], *pva = (const float*)d_in[21];

  float* out = (float*)d_out;       // outputs in return order
  float* xs  = out + NE1;
  float* dq  = out + 2 * NE1;
  float* dk  = out + 3 * NE1;
  float* dv  = out + 4 * NE1;

  char* ws = (char*)d_ws;
  unsigned short* xbits = (unsigned short*)ws;                  // 4194304 B
  unsigned short* Wqkv  = (unsigned short*)(ws + 4194304);      // 1179648 B
  unsigned short* Wp    = (unsigned short*)(ws + 5373952);      // 393216 B
  unsigned short* qbits = (unsigned short*)(ws + 5767168);      // 4194304 B
  unsigned short* kbits = (unsigned short*)(ws + 9961472);      // 4194304 B
  unsigned short* vbits = (unsigned short*)(ws + 14155776);     // 4194304 B
  unsigned short* sbits = (unsigned short*)(ws + 18350080);     // 4194304 B
  unsigned short* kvhiT = (unsigned short*)(ws + 22544384);     // 524288 B
  unsigned short* kvloT = (unsigned short*)(ws + 23068672);     // 524288 B
  float* invqkv         = (float*)(ws + 23592960);              // 768 floats
  float* shqkv          = invqkv + 768;
  float* invp           = shqkv + 768;
  float* shp            = invp + 256;

  prep_kernel<<<1028, 256, 0, stream>>>(wq, wk, wv, wp, bp,
                                        qg, qb, qm, qva, kg, kb, km, kva,
                                        vg, vb, vm, vva, pg, pb, pm, pva,
                                        Wqkv, Wp, invqkv, shqkv, invp, shp);
  lifx_kernel<<<dim3(64, 4, 16), 256, 0, stream>>>(x, xs, xbits);
  qkv_gemm<<<dim3(64, 6, 16), 256, 0, stream>>>((const unsigned int*)xbits, Wqkv,
                                                invqkv, shqkv, dq, dk, dv,
                                                qbits, kbits, vbits);
  kv_kernel<<<dim3(8, 32), 256, 0, stream>>>((const unsigned long long*)kbits,
                                             (const unsigned long long*)vbits,
                                             kvhiT, kvloT);
  attn_kernel<<<dim3(16, 8, 16), 256, 0, stream>>>(qbits, kvhiT, kvloT, sbits);
  p_gemm<<<dim3(32, 2, 32), 256, 0, stream>>>((const unsigned int*)sbits, Wp,
                                              invp, shp, out);
}